// Round 17
// baseline (703.908 us; speedup 1.0000x reference)
//
#include <hip/hip_runtime.h>
#include <hip/hip_bf16.h>

typedef __attribute__((ext_vector_type(8))) short short8_t;
typedef __attribute__((ext_vector_type(8))) __bf16 bf16x8;
typedef __attribute__((ext_vector_type(4))) float f32x4;
typedef __attribute__((ext_vector_type(16))) float f32x16;

__device__ __forceinline__ void gload16(const void* g, void* l) {
  __builtin_amdgcn_global_load_lds(
      (const __attribute__((address_space(1))) void*)g,
      (__attribute__((address_space(3))) void*)l, 16, 0, 0);
}

__device__ __forceinline__ unsigned short f2bf(float f) {
  __hip_bfloat16 h = __float2bfloat16(f);
  return __builtin_bit_cast(unsigned short, h);
}

#define BARRIER() asm volatile("s_barrier" ::: "memory")

// ---------------- conversion kernels ----------------

__global__ void k_cvt_feat(const float* __restrict__ in, unsigned short* __restrict__ out) {
  const size_t N = (size_t)4096 * 8192;
  size_t i = ((size_t)blockIdx.x * 256 + threadIdx.x) * 4;
  const size_t stride = (size_t)gridDim.x * 256 * 4;
  for (; i < N; i += stride) {
    float4 v = *(const float4*)(in + i);
    ushort4 o;
    o.x = f2bf(v.x); o.y = f2bf(v.y); o.z = f2bf(v.z); o.w = f2bf(v.w);
    *(ushort4*)(out + i) = o;
  }
}

// W1 f32 [p][8192][256] -> bf16 transposed chunk-local [z][256][8192]
__global__ void k_cvt_w1(const float* __restrict__ W1, unsigned short* __restrict__ out, int p0) {
  __shared__ unsigned short t[64][262];
  const int p = p0 + blockIdx.z;
  const float* src = W1 + (size_t)p * 8192 * 256;
  unsigned short* dst = out + (size_t)blockIdx.z * 256 * 8192;
  const int f0 = blockIdx.x * 256, h0 = blockIdx.y * 64;
#pragma unroll
  for (int i = 0; i < 64; ++i) {
    int tt = i * 256 + threadIdx.x;
    int f = tt >> 6, c = tt & 63;
    t[c][f] = f2bf(src[(size_t)(f0 + f) * 256 + h0 + c]);
  }
  __syncthreads();
#pragma unroll
  for (int i = 0; i < 8; ++i) {
    int tt = i * 256 + threadIdx.x;
    int r = tt >> 5;
    int c8 = (tt & 31) * 8;
    short8_t o;
#pragma unroll
    for (int j = 0; j < 8; ++j) o[j] = (short)t[r][c8 + j];
    *(short8_t*)&dst[(size_t)(h0 + r) * 8192 + f0 + c8] = o;
  }
}

// W2 f32 [p][256][128] -> bf16 transposed [p][128][256]
__global__ void k_cvt_w2(const float* __restrict__ W2, unsigned short* __restrict__ out) {
  const int p = blockIdx.x;
  const float* src = W2 + (size_t)p * 256 * 128;
  unsigned short* dst = out + (size_t)p * 128 * 256;
  for (int tt = threadIdx.x; tt < 128 * 256; tt += 256) {
    int j = tt >> 8, h = tt & 255;
    dst[tt] = f2bf(src[(size_t)h * 128 + j]);
  }
}

// -------- FUSED: out = sigmoid(relu(relu(feat@W1+b1)@W2+b2)@W3+b3) --------
// r14 champion schedule + 32x32x16 MFMA + COLUMN-MAJOR-BY-UNIT LDS layout.
// Half-tile = [128 rows][8 units of 16B]; unit (r,u) stored at slot u*128+r.
// A 32-row frag read (fixed u, r=0..31) = 512B consecutive = clean burst,
// 0 bank conflicts (fixes r8's derivable 4-way conflict: row-major rows
// give only 8 permutable unit slots for 32 rows -> pigeonhole 4-way).
// Layout realized via pre-permuted global source (rule 21): stage slot
// e = i*512+tid -> u=e>>7, r=e&127 -> src r*8192+u*8; LDS dest stays linear.
// Schedule (identical barriers/stage-slots/vmcnt(6) to r14 champion):
//  ph1: [BAR] rd bh(t)      | stage A1(t+1)->nx | 8 MFMA Q00 (aH0 x bl)
//  ph2: [BAR] rd aH1(t)     | stage A0(t+2)->c  | 8 MFMA Q01 (aH0 x bh)
//  ph3: [BAR]               | stage B1(t+2)->c  | 8 MFMA Q10 (aH1 x bl)
//  ph4: [BAR] stage B0(t+2)->c | vmcnt(6) [BAR] rd aH0,bl(t+1)<-nx | Q11
// NOTE (r13/r15): never hoist swizzled offsets into persistent arrays --
// scratch demotion (WRITE_SIZE 4->32/44MB). Keep addresses inline.
__global__ __launch_bounds__(512, 2) void k_gemm1(
    const unsigned short* __restrict__ A,    // [4096][8192] bf16
    const unsigned short* __restrict__ Bt,   // [z][256][8192] bf16
    const float* __restrict__ b1,            // [29][256]
    const unsigned short* __restrict__ W2t,  // [29][128][256] bf16
    const float* __restrict__ b2,            // [29][128]
    const float* __restrict__ W3,            // [29][128]
    const float* __restrict__ b3,            // [29]
    float* __restrict__ out,                 // [4096][29]
    int p0) {
  __shared__ __align__(16) unsigned short S[65536];  // 128 KiB

  const int tid = threadIdx.x;
  const int lane = tid & 63;
  const int wave = tid >> 6;
  const int sr = (wave >> 2) * 64;   // wave's 64-row slice within 128-row half
  const int sc = (wave & 3) * 32;    // wave's 32-col slice within 128-col half

  const int nwg = gridDim.x * gridDim.y;
  const int orig = blockIdx.y * gridDim.x + blockIdx.x;
  const int q = nwg >> 3, r_ = nwg & 7;
  const int xcd = orig & 7, idx = orig >> 3;
  const int wg = (xcd < r_ ? xcd * (q + 1) : r_ * (q + 1) + (xcd - r_) * q) + idx;
  const int mx = wg & 15;     // gridDim.x == 16
  const int z = wg >> 4;
  const int p = p0 + z;
  const int m0 = mx * 256;

  const unsigned short* Ab = A + (size_t)m0 * 8192;
  const unsigned short* Bb = Bt + (size_t)z * 256 * 8192;

  // staging: slot e = i*512+tid; u = e>>7 (16B unit), r = e&127 (row);
  // source element (r, u) -> column-major-by-unit LDS (dest linear).
  int e0 = tid, u0 = e0 >> 7, r0 = e0 & 127;
  int e1 = 512 + tid, u1 = e1 >> 7, r1e = e1 & 127;
  const size_t s0 = (size_t)r0 * 8192 + u0 * 8;
  const size_t s1 = (size_t)r1e * 8192 + u1 * 8;
  const int ld0 = (wave * 64) * 8;
  const int ld1 = (512 + wave * 64) * 8;

  auto stage = [&](int buf, int isB, int h, int T) {
    const unsigned short* gb = (isB ? Bb : Ab) + (size_t)h * 128 * 8192 + (size_t)T * 64;
    unsigned short* lb = S + buf * 32768 + isB * 16384 + h * 8192;
    gload16(gb + s0, lb + ld0);
    gload16(gb + s1, lb + ld1);
  };

  const int l15 = lane & 15, ks = lane >> 4;   // for epilogue GEMM2 (16x16)
  const int l31 = lane & 31, ks2 = lane >> 5;  // for main loop (32x32)

  // frag reads: slot = u*128 + R -> short offset u*1024 + R*8
  auto rdA = [&](int buf, int h, int mi2, int kx) {
    int R = sr + mi2 * 32 + l31;
    int u = kx * 2 + ks2;
    return __builtin_bit_cast(bf16x8, *(const short8_t*)(S + buf * 32768 + h * 8192 + u * 1024 + R * 8));
  };
  auto rdB = [&](int buf, int v, int kx) {
    int R = sc + l31;
    int u = kx * 2 + ks2;
    return __builtin_bit_cast(bf16x8, *(const short8_t*)(S + buf * 32768 + 16384 + v * 8192 + u * 1024 + R * 8));
  };

  f32x16 acc[4][2] = {};     // [quadrant qh*2+qv][mi2]
  bf16x8 aH0[2][4], aH1[2][4], blf[4], bhf[4];
  const int NT = 8192 / 64;  // 128 K-tiles

  auto kstep = [&](int t, int pfa, int pf, int ra, int vm) {
    const int c = t & 1, nx = c ^ 1;
    // ---- ph1: rd bh | stage A1(t+1)->nx | MFMA Q00 (aH0 x bl) ----
    BARRIER();
#pragma unroll
    for (int kx = 0; kx < 4; ++kx) bhf[kx] = rdB(c, 1, kx);
    if (pfa) stage(nx, 0, 1, t + 1);
    __builtin_amdgcn_s_setprio(1);
#pragma unroll
    for (int kx = 0; kx < 4; ++kx)
#pragma unroll
      for (int mi2 = 0; mi2 < 2; ++mi2)
        acc[0][mi2] = __builtin_amdgcn_mfma_f32_32x32x16_bf16(aH0[mi2][kx], blf[kx], acc[0][mi2], 0, 0, 0);
    __builtin_amdgcn_s_setprio(0);
    // ---- ph2: rd aH1 | stage A0(t+2)->c | MFMA Q01 (aH0 x bh) ----
    BARRIER();
#pragma unroll
    for (int mi2 = 0; mi2 < 2; ++mi2)
#pragma unroll
      for (int kx = 0; kx < 4; ++kx) aH1[mi2][kx] = rdA(c, 1, mi2, kx);
    if (pf) stage(c, 0, 0, t + 2);
    __builtin_amdgcn_s_setprio(1);
#pragma unroll
    for (int kx = 0; kx < 4; ++kx)
#pragma unroll
      for (int mi2 = 0; mi2 < 2; ++mi2)
        acc[1][mi2] = __builtin_amdgcn_mfma_f32_32x32x16_bf16(aH0[mi2][kx], bhf[kx], acc[1][mi2], 0, 0, 0);
    __builtin_amdgcn_s_setprio(0);
    // ---- ph3: stage B1(t+2)->c | MFMA Q10 (aH1 x bl) ----
    BARRIER();
    if (pf) stage(c, 1, 1, t + 2);
    __builtin_amdgcn_s_setprio(1);
#pragma unroll
    for (int kx = 0; kx < 4; ++kx)
#pragma unroll
      for (int mi2 = 0; mi2 < 2; ++mi2)
        acc[2][mi2] = __builtin_amdgcn_mfma_f32_32x32x16_bf16(aH1[mi2][kx], blf[kx], acc[2][mi2], 0, 0, 0);
    __builtin_amdgcn_s_setprio(0);
    // ---- ph4: stage B0(t+2)->c | vmcnt | BAR | read-ahead (t+1)<-nx | Q11 ----
    BARRIER();
    if (pf) stage(c, 1, 0, t + 2);
    if (vm == 6)      asm volatile("s_waitcnt vmcnt(6)" ::: "memory");
    else if (vm == 0) asm volatile("s_waitcnt vmcnt(0)" ::: "memory");
    BARRIER();
    if (ra) {
#pragma unroll
      for (int mi2 = 0; mi2 < 2; ++mi2)
#pragma unroll
        for (int kx = 0; kx < 4; ++kx) aH0[mi2][kx] = rdA(nx, 0, mi2, kx);
#pragma unroll
      for (int kx = 0; kx < 4; ++kx) blf[kx] = rdB(nx, 0, kx);
    }
    __builtin_amdgcn_s_setprio(1);
#pragma unroll
    for (int kx = 0; kx < 4; ++kx)
#pragma unroll
      for (int mi2 = 0; mi2 < 2; ++mi2)
        acc[3][mi2] = __builtin_amdgcn_mfma_f32_32x32x16_bf16(aH1[mi2][kx], bhf[kx], acc[3][mi2], 0, 0, 0);
    __builtin_amdgcn_s_setprio(0);
  };

  // prologue: tile0 {A0,B0,B1,A1}, tile1 {A0,B1,B0}; vmcnt(6) retires tile0;
  // then initial reads aH0(0), bl(0).
  stage(0, 0, 0, 0); stage(0, 1, 0, 0); stage(0, 1, 1, 0); stage(0, 0, 1, 0);
  stage(1, 0, 0, 1); stage(1, 1, 1, 1); stage(1, 1, 0, 1);
  asm volatile("s_waitcnt vmcnt(6)" ::: "memory");
  BARRIER();
#pragma unroll
  for (int mi2 = 0; mi2 < 2; ++mi2)
#pragma unroll
    for (int kx = 0; kx < 4; ++kx) aH0[mi2][kx] = rdA(0, 0, mi2, kx);
#pragma unroll
  for (int kx = 0; kx < 4; ++kx) blf[kx] = rdB(0, 0, kx);

  for (int t = 0; t < NT - 2; ++t) kstep(t, 1, 1, 1, 6);
  kstep(NT - 2, 1, 0, 1, 0);
  kstep(NT - 1, 0, 0, 0, -1);

  // ---- fused epilogue ----
  // 1) h1 = relu(acc + b1) -> LDS [256 rows][32 units of 16B], unit u of
  //    row R at phys u^(R&7) (16x16-friendly layout for GEMM2 reads).
  //    32x32 C/D mapping: col = lane&31, row = (rg&3)+8*(rg>>2)+4*(lane>>5).
  __syncthreads();
  {
#pragma unroll
    for (int qh = 0; qh < 2; ++qh)
#pragma unroll
      for (int qv = 0; qv < 2; ++qv) {
        const int qq = qh * 2 + qv;
        const int col = qv * 128 + sc + l31;
        const float bb = b1[p * 256 + col];
        const int u = col >> 3, sub = col & 7;
#pragma unroll
        for (int mi2 = 0; mi2 < 2; ++mi2) {
          const int Rb = qh * 128 + sr + mi2 * 32 + 4 * ks2;
#pragma unroll
          for (int rg = 0; rg < 16; ++rg) {
            const int R = Rb + (rg & 3) + 8 * (rg >> 2);
            float v = acc[qq][mi2][rg] + bb;
            v = v > 0.f ? v : 0.f;
            S[R * 256 + ((u ^ (R & 7)) * 8) + sub] = f2bf(v);
          }
        }
      }
  }
  __syncthreads();
  // 2) GEMM2: wave owns rows wave*32..+32, cols 0..127, K=256; A from LDS,
  //    B=W2t frags from global (L2-resident). (unchanged from champion)
  {
    const unsigned short* Wp = W2t + (size_t)p * 128 * 256;
    f32x4 acc2[2][8] = {};
    bf16x8 bcur[8], bnxt[8];
#pragma unroll
    for (int nj = 0; nj < 8; ++nj)
      bcur[nj] = __builtin_bit_cast(bf16x8, *(const short8_t*)(Wp + (nj * 16 + l15) * 256 + ks * 8));
#pragma unroll
    for (int kt = 0; kt < 8; ++kt) {
      if (kt < 7) {
#pragma unroll
        for (int nj = 0; nj < 8; ++nj)
          bnxt[nj] = __builtin_bit_cast(bf16x8, *(const short8_t*)(Wp + (nj * 16 + l15) * 256 + (kt + 1) * 32 + ks * 8));
      }
      bf16x8 a2[2];
#pragma unroll
      for (int mi = 0; mi < 2; ++mi) {
        const int R = wave * 32 + mi * 16 + l15;
        const int u = kt * 4 + ks;
        a2[mi] = __builtin_bit_cast(bf16x8, *(const short8_t*)(S + R * 256 + ((u ^ (R & 7)) * 8)));
      }
#pragma unroll
      for (int mi = 0; mi < 2; ++mi)
#pragma unroll
        for (int nj = 0; nj < 8; ++nj)
          acc2[mi][nj] = __builtin_amdgcn_mfma_f32_16x16x32_bf16(a2[mi], bcur[nj], acc2[mi][nj], 0, 0, 0);
#pragma unroll
      for (int nj = 0; nj < 8; ++nj) bcur[nj] = bnxt[nj];
    }
    float b2v[8], w3v[8];
#pragma unroll
    for (int nj = 0; nj < 8; ++nj) {
      int c = nj * 16 + l15;
      b2v[nj] = b2[p * 128 + c];
      w3v[nj] = W3[p * 128 + c];
    }
    const float b3p = b3[p];
#pragma unroll
    for (int mi = 0; mi < 2; ++mi) {
#pragma unroll
      for (int r = 0; r < 4; ++r) {
        float s = 0.f;
#pragma unroll
        for (int nj = 0; nj < 8; ++nj) {
          float v = acc2[mi][nj][r] + b2v[nj];
          v = v > 0.f ? v : 0.f;
          s += v * w3v[nj];
        }
        s += __shfl_xor(s, 1);
        s += __shfl_xor(s, 2);
        s += __shfl_xor(s, 4);
        s += __shfl_xor(s, 8);
        if (l15 == 0) {
          int m = m0 + wave * 32 + mi * 16 + ks * 4 + r;
          float logit = s + b3p;
          out[(size_t)m * 29 + p] = 1.f / (1.f + __expf(-logit));
        }
      }
    }
  }
}

// ---------------- launch ----------------
extern "C" void kernel_launch(void* const* d_in, const int* in_sizes, int n_in,
                              void* d_out, int out_size, void* d_ws, size_t ws_size,
                              hipStream_t stream) {
  const float* features = (const float*)d_in[0];
  const float* W1 = (const float*)d_in[1];
  const float* b1 = (const float*)d_in[2];
  const float* W2 = (const float*)d_in[3];
  const float* b2 = (const float*)d_in[4];
  const float* W3 = (const float*)d_in[5];
  const float* b3 = (const float*)d_in[6];
  float* out = (float*)d_out;

  char* ws = (char*)d_ws;
  const size_t featB = (size_t)4096 * 8192 * 2;       // 64 MB
  const size_t w2B   = (size_t)29 * 128 * 256 * 2;    // 1.9 MB
  const size_t w1pp  = (size_t)256 * 8192 * 2;        // 4 MB per predicate

  unsigned short* featbf = (unsigned short*)ws;
  unsigned short* w2t    = (unsigned short*)(ws + featB);
  unsigned short* w1t    = (unsigned short*)(ws + featB + w2B);

  size_t base = featB + w2B;
  size_t rem = (ws_size > base) ? (ws_size - base) : 0;
  int CH = (int)(rem / w1pp);
  if (CH > 29) CH = 29;
  if (CH < 1) CH = 1;

  k_cvt_feat<<<2048, 256, 0, stream>>>(features, featbf);
  k_cvt_w2<<<29, 256, 0, stream>>>(W2, w2t);

  for (int p0 = 0; p0 < 29; p0 += CH) {
    int c = (29 - p0) < CH ? (29 - p0) : CH;
    k_cvt_w1<<<dim3(32, 4, c), 256, 0, stream>>>(W1, w1t, p0);
    k_gemm1<<<dim3(16, c), 512, 0, stream>>>(featbf, w1t, b1, w2t, b2, W3, b3, out, p0);
  }
}

// Round 18
// 531.094 us; speedup vs baseline: 1.3254x; 1.3254x over previous
//
#include <hip/hip_runtime.h>
#include <hip/hip_bf16.h>

typedef __attribute__((ext_vector_type(8))) short short8_t;
typedef __attribute__((ext_vector_type(8))) __bf16 bf16x8;
typedef __attribute__((ext_vector_type(4))) float f32x4;

__device__ __forceinline__ void gload16(const void* g, void* l) {
  __builtin_amdgcn_global_load_lds(
      (const __attribute__((address_space(1))) void*)g,
      (__attribute__((address_space(3))) void*)l, 16, 0, 0);
}

__device__ __forceinline__ unsigned short f2bf(float f) {
  __hip_bfloat16 h = __float2bfloat16(f);
  return __builtin_bit_cast(unsigned short, h);
}

#define BARRIER() asm volatile("s_barrier" ::: "memory")

// ---------------- conversion kernels ----------------

__global__ void k_cvt_feat(const float* __restrict__ in, unsigned short* __restrict__ out) {
  const size_t N = (size_t)4096 * 8192;
  size_t i = ((size_t)blockIdx.x * 256 + threadIdx.x) * 4;
  const size_t stride = (size_t)gridDim.x * 256 * 4;
  for (; i < N; i += stride) {
    float4 v = *(const float4*)(in + i);
    ushort4 o;
    o.x = f2bf(v.x); o.y = f2bf(v.y); o.z = f2bf(v.z); o.w = f2bf(v.w);
    *(ushort4*)(out + i) = o;
  }
}

// W1 f32 [p][8192][256] -> bf16 transposed chunk-local [z][256][8192]
__global__ void k_cvt_w1(const float* __restrict__ W1, unsigned short* __restrict__ out, int p0) {
  __shared__ unsigned short t[64][262];
  const int p = p0 + blockIdx.z;
  const float* src = W1 + (size_t)p * 8192 * 256;
  unsigned short* dst = out + (size_t)blockIdx.z * 256 * 8192;
  const int f0 = blockIdx.x * 256, h0 = blockIdx.y * 64;
#pragma unroll
  for (int i = 0; i < 64; ++i) {
    int tt = i * 256 + threadIdx.x;
    int f = tt >> 6, c = tt & 63;
    t[c][f] = f2bf(src[(size_t)(f0 + f) * 256 + h0 + c]);
  }
  __syncthreads();
#pragma unroll
  for (int i = 0; i < 8; ++i) {
    int tt = i * 256 + threadIdx.x;
    int r = tt >> 5;
    int c8 = (tt & 31) * 8;
    short8_t o;
#pragma unroll
    for (int j = 0; j < 8; ++j) o[j] = (short)t[r][c8 + j];
    *(short8_t*)&dst[(size_t)(h0 + r) * 8192 + f0 + c8] = o;
  }
}

// W2 f32 [p][256][128] -> bf16 transposed [p][128][256]
__global__ void k_cvt_w2(const float* __restrict__ W2, unsigned short* __restrict__ out) {
  const int p = blockIdx.x;
  const float* src = W2 + (size_t)p * 256 * 128;
  unsigned short* dst = out + (size_t)p * 128 * 256;
  for (int tt = threadIdx.x; tt < 128 * 256; tt += 256) {
    int j = tt >> 8, h = tt & 255;
    dst[tt] = f2bf(src[(size_t)h * 128 + j]);
  }
}

// -------- FUSED: out = sigmoid(relu(relu(feat@W1+b1)@W2+b2)@W3+b3) --------
// CHAMPION (r11/r14/r16, 531.6-534.2us total): quadrant pipeline + read-ahead.
//  ph1: [BAR] rd bh(t)      | stage A1(t+1)->nx | MFMA Q00 (aH0 x bl)
//  ph2: [BAR] rd aH1(t)     | stage A0(t+2)->c  | MFMA Q01 (aH0 x bh)
//  ph3: [BAR]               | stage B1(t+2)->c  | MFMA Q10 (aH1 x bl)
//  ph4: [BAR] stage B0(t+2)->c | vmcnt(6) [BAR] rd aH0,bl(t+1)<-nx | MFMA Q11
// Hazards: every overwrite >=1 barrier after its slot's readers drain.
// FIFO: wait@ph4(t) vmcnt(6) retires through tile t+1, keeps {A0,B1,B0}(t+2).
// Negative results pinned (do not retry):
//  - hoisting swizzled offsets into persistent arrays -> scratch (r13/r15)
//  - 32x32 MFMA: row-major LDS = 4-way conflict (r8); col-major LDS =
//    uncoalesced gload_lds source (r17). 16x16 + 8-unit XOR is the fixed point.
//  - pipe separation (A via per-lane global loads): latency-bound (r12)
//  - 2 blocks/CU via 128-row tile: FETCH x2, L3 thrash (r7)
__global__ __launch_bounds__(512, 2) void k_gemm1(
    const unsigned short* __restrict__ A,    // [4096][8192] bf16
    const unsigned short* __restrict__ Bt,   // [z][256][8192] bf16
    const float* __restrict__ b1,            // [29][256]
    const unsigned short* __restrict__ W2t,  // [29][128][256] bf16
    const float* __restrict__ b2,            // [29][128]
    const float* __restrict__ W3,            // [29][128]
    const float* __restrict__ b3,            // [29]
    float* __restrict__ out,                 // [4096][29]
    int p0) {
  __shared__ __align__(16) unsigned short S[65536];  // 128 KiB

  const int tid = threadIdx.x;
  const int lane = tid & 63;
  const int wave = tid >> 6;
  const int sr = (wave >> 2) * 64;
  const int sc = (wave & 3) * 32;

  const int nwg = gridDim.x * gridDim.y;
  const int orig = blockIdx.y * gridDim.x + blockIdx.x;
  const int q = nwg >> 3, r_ = nwg & 7;
  const int xcd = orig & 7, idx = orig >> 3;
  const int wg = (xcd < r_ ? xcd * (q + 1) : r_ * (q + 1) + (xcd - r_) * q) + idx;
  const int mx = wg & 15;     // gridDim.x == 16
  const int z = wg >> 4;
  const int p = p0 + z;
  const int m0 = mx * 256;

  const unsigned short* Ab = A + (size_t)m0 * 8192;
  const unsigned short* Bb = Bt + (size_t)z * 256 * 8192;

  int e0 = tid, r0 = e0 >> 3, u0 = (e0 & 7) ^ (r0 & 7);
  int e1 = 512 + tid, r1e = e1 >> 3, u1 = (e1 & 7) ^ (r1e & 7);
  const size_t s0 = (size_t)r0 * 8192 + u0 * 8;
  const size_t s1 = (size_t)r1e * 8192 + u1 * 8;
  const int ld0 = (wave * 64) * 8;
  const int ld1 = (512 + wave * 64) * 8;

  auto stage = [&](int buf, int isB, int h, int T) {
    const unsigned short* gb = (isB ? Bb : Ab) + (size_t)h * 128 * 8192 + (size_t)T * 64;
    unsigned short* lb = S + buf * 32768 + isB * 16384 + h * 8192;
    gload16(gb + s0, lb + ld0);
    gload16(gb + s1, lb + ld1);
  };

  const int l15 = lane & 15, ks = lane >> 4;

  auto rdA = [&](int buf, int h, int mi, int x) {
    int R = sr + mi * 16 + l15;
    int pu = (x * 4 + ks) ^ (R & 7);
    return __builtin_bit_cast(bf16x8, *(const short8_t*)(S + buf * 32768 + h * 8192 + R * 64 + pu * 8));
  };
  auto rdB = [&](int buf, int v, int nj, int x) {
    int R = sc + nj * 16 + l15;
    int pu = (x * 4 + ks) ^ (R & 7);
    return __builtin_bit_cast(bf16x8, *(const short8_t*)(S + buf * 32768 + 16384 + v * 8192 + R * 64 + pu * 8));
  };

  f32x4 acc[4][4][2] = {};   // [quadrant][mi][nj]
  bf16x8 aH0[4][2], aH1[4][2], blf[2][2], bhf[2][2];
  const int NT = 8192 / 64;  // 128 K-tiles

  auto kstep = [&](int t, int pfa, int pf, int ra, int vm) {
    const int c = t & 1, nx = c ^ 1;
    // ---- ph1: rd bh | stage A1(t+1) | MFMA Q00 (aH0 x bl, read @ph4(t-1)) ----
    BARRIER();
#pragma unroll
    for (int nj = 0; nj < 2; ++nj) { bhf[nj][0] = rdB(c, 1, nj, 0); bhf[nj][1] = rdB(c, 1, nj, 1); }
    if (pfa) stage(nx, 0, 1, t + 1);
    __builtin_amdgcn_s_setprio(1);
#pragma unroll
    for (int mi = 0; mi < 4; ++mi)
#pragma unroll
      for (int nj = 0; nj < 2; ++nj) {
        acc[0][mi][nj] = __builtin_amdgcn_mfma_f32_16x16x32_bf16(aH0[mi][0], blf[nj][0], acc[0][mi][nj], 0, 0, 0);
        acc[0][mi][nj] = __builtin_amdgcn_mfma_f32_16x16x32_bf16(aH0[mi][1], blf[nj][1], acc[0][mi][nj], 0, 0, 0);
      }
    __builtin_amdgcn_s_setprio(0);
    // ---- ph2: rd aH1 | stage A0(t+2) | MFMA Q01 (aH0 x bh) ----
    BARRIER();
#pragma unroll
    for (int mi = 0; mi < 4; ++mi) { aH1[mi][0] = rdA(c, 1, mi, 0); aH1[mi][1] = rdA(c, 1, mi, 1); }
    if (pf) stage(c, 0, 0, t + 2);
    __builtin_amdgcn_s_setprio(1);
#pragma unroll
    for (int mi = 0; mi < 4; ++mi)
#pragma unroll
      for (int nj = 0; nj < 2; ++nj) {
        acc[1][mi][nj] = __builtin_amdgcn_mfma_f32_16x16x32_bf16(aH0[mi][0], bhf[nj][0], acc[1][mi][nj], 0, 0, 0);
        acc[1][mi][nj] = __builtin_amdgcn_mfma_f32_16x16x32_bf16(aH0[mi][1], bhf[nj][1], acc[1][mi][nj], 0, 0, 0);
      }
    __builtin_amdgcn_s_setprio(0);
    // ---- ph3: stage B1(t+2) | MFMA Q10 (aH1 x bl) ----
    BARRIER();
    if (pf) stage(c, 1, 1, t + 2);
    __builtin_amdgcn_s_setprio(1);
#pragma unroll
    for (int mi = 0; mi < 4; ++mi)
#pragma unroll
      for (int nj = 0; nj < 2; ++nj) {
        acc[2][mi][nj] = __builtin_amdgcn_mfma_f32_16x16x32_bf16(aH1[mi][0], blf[nj][0], acc[2][mi][nj], 0, 0, 0);
        acc[2][mi][nj] = __builtin_amdgcn_mfma_f32_16x16x32_bf16(aH1[mi][1], blf[nj][1], acc[2][mi][nj], 0, 0, 0);
      }
    __builtin_amdgcn_s_setprio(0);
    // ---- ph4: stage B0(t+2) | vmcnt | BAR | read-ahead aH0,bl(t+1) | MFMA Q11 ----
    BARRIER();
    if (pf) stage(c, 1, 0, t + 2);
    if (vm == 6)      asm volatile("s_waitcnt vmcnt(6)" ::: "memory");
    else if (vm == 0) asm volatile("s_waitcnt vmcnt(0)" ::: "memory");
    BARRIER();
    if (ra) {
#pragma unroll
      for (int mi = 0; mi < 4; ++mi) { aH0[mi][0] = rdA(nx, 0, mi, 0); aH0[mi][1] = rdA(nx, 0, mi, 1); }
#pragma unroll
      for (int nj = 0; nj < 2; ++nj) { blf[nj][0] = rdB(nx, 0, nj, 0); blf[nj][1] = rdB(nx, 0, nj, 1); }
    }
    __builtin_amdgcn_s_setprio(1);
#pragma unroll
    for (int mi = 0; mi < 4; ++mi)
#pragma unroll
      for (int nj = 0; nj < 2; ++nj) {
        acc[3][mi][nj] = __builtin_amdgcn_mfma_f32_16x16x32_bf16(aH1[mi][0], bhf[nj][0], acc[3][mi][nj], 0, 0, 0);
        acc[3][mi][nj] = __builtin_amdgcn_mfma_f32_16x16x32_bf16(aH1[mi][1], bhf[nj][1], acc[3][mi][nj], 0, 0, 0);
      }
    __builtin_amdgcn_s_setprio(0);
  };

  // prologue: tile0 {A0,B0,B1,A1}, tile1 {A0,B1,B0}; vmcnt(6) retires tile0;
  // then initial reads aH0(0), bl(0).
  stage(0, 0, 0, 0); stage(0, 1, 0, 0); stage(0, 1, 1, 0); stage(0, 0, 1, 0);
  stage(1, 0, 0, 1); stage(1, 1, 1, 1); stage(1, 1, 0, 1);
  asm volatile("s_waitcnt vmcnt(6)" ::: "memory");
  BARRIER();
#pragma unroll
  for (int mi = 0; mi < 4; ++mi) { aH0[mi][0] = rdA(0, 0, mi, 0); aH0[mi][1] = rdA(0, 0, mi, 1); }
#pragma unroll
  for (int nj = 0; nj < 2; ++nj) { blf[nj][0] = rdB(0, 0, nj, 0); blf[nj][1] = rdB(0, 0, nj, 1); }

  for (int t = 0; t < NT - 2; ++t) kstep(t, 1, 1, 1, 6);
  kstep(NT - 2, 1, 0, 1, 0);
  kstep(NT - 1, 0, 0, 0, -1);

  // ---- fused epilogue ----
  __syncthreads();
  {
    const int rg = lane >> 4;
#pragma unroll
    for (int qh = 0; qh < 2; ++qh)
#pragma unroll
      for (int qv = 0; qv < 2; ++qv) {
        const int qq = qh * 2 + qv;
#pragma unroll
        for (int nj = 0; nj < 2; ++nj) {
          const int c = qv * 128 + sc + nj * 16 + l15;
          const float bb = b1[p * 256 + c];
          const int u = c >> 3, sub = c & 7;
#pragma unroll
          for (int mi = 0; mi < 4; ++mi) {
            const int Rb = qh * 128 + sr + mi * 16 + rg * 4;
#pragma unroll
            for (int rr = 0; rr < 4; ++rr) {
              const int R = Rb + rr;
              float v = acc[qq][mi][nj][rr] + bb;
              v = v > 0.f ? v : 0.f;
              S[R * 256 + ((u ^ (R & 7)) * 8) + sub] = f2bf(v);
            }
          }
        }
      }
  }
  __syncthreads();
  {
    const unsigned short* Wp = W2t + (size_t)p * 128 * 256;
    f32x4 acc2[2][8] = {};
    bf16x8 bcur[8], bnxt[8];
#pragma unroll
    for (int nj = 0; nj < 8; ++nj)
      bcur[nj] = __builtin_bit_cast(bf16x8, *(const short8_t*)(Wp + (nj * 16 + l15) * 256 + ks * 8));
#pragma unroll
    for (int kt = 0; kt < 8; ++kt) {
      if (kt < 7) {
#pragma unroll
        for (int nj = 0; nj < 8; ++nj)
          bnxt[nj] = __builtin_bit_cast(bf16x8, *(const short8_t*)(Wp + (nj * 16 + l15) * 256 + (kt + 1) * 32 + ks * 8));
      }
      bf16x8 a2[2];
#pragma unroll
      for (int mi = 0; mi < 2; ++mi) {
        const int R = wave * 32 + mi * 16 + l15;
        const int u = kt * 4 + ks;
        a2[mi] = __builtin_bit_cast(bf16x8, *(const short8_t*)(S + R * 256 + ((u ^ (R & 7)) * 8)));
      }
#pragma unroll
      for (int mi = 0; mi < 2; ++mi)
#pragma unroll
        for (int nj = 0; nj < 8; ++nj)
          acc2[mi][nj] = __builtin_amdgcn_mfma_f32_16x16x32_bf16(a2[mi], bcur[nj], acc2[mi][nj], 0, 0, 0);
#pragma unroll
      for (int nj = 0; nj < 8; ++nj) bcur[nj] = bnxt[nj];
    }
    float b2v[8], w3v[8];
#pragma unroll
    for (int nj = 0; nj < 8; ++nj) {
      int c = nj * 16 + l15;
      b2v[nj] = b2[p * 128 + c];
      w3v[nj] = W3[p * 128 + c];
    }
    const float b3p = b3[p];
#pragma unroll
    for (int mi = 0; mi < 2; ++mi) {
#pragma unroll
      for (int r = 0; r < 4; ++r) {
        float s = 0.f;
#pragma unroll
        for (int nj = 0; nj < 8; ++nj) {
          float v = acc2[mi][nj][r] + b2v[nj];
          v = v > 0.f ? v : 0.f;
          s += v * w3v[nj];
        }
        s += __shfl_xor(s, 1);
        s += __shfl_xor(s, 2);
        s += __shfl_xor(s, 4);
        s += __shfl_xor(s, 8);
        if (l15 == 0) {
          int m = m0 + wave * 32 + mi * 16 + ks * 4 + r;
          float logit = s + b3p;
          out[(size_t)m * 29 + p] = 1.f / (1.f + __expf(-logit));
        }
      }
    }
  }
}

// ---------------- launch ----------------
extern "C" void kernel_launch(void* const* d_in, const int* in_sizes, int n_in,
                              void* d_out, int out_size, void* d_ws, size_t ws_size,
                              hipStream_t stream) {
  const float* features = (const float*)d_in[0];
  const float* W1 = (const float*)d_in[1];
  const float* b1 = (const float*)d_in[2];
  const float* W2 = (const float*)d_in[3];
  const float* b2 = (const float*)d_in[4];
  const float* W3 = (const float*)d_in[5];
  const float* b3 = (const float*)d_in[6];
  float* out = (float*)d_out;

  char* ws = (char*)d_ws;
  const size_t featB = (size_t)4096 * 8192 * 2;       // 64 MB
  const size_t w2B   = (size_t)29 * 128 * 256 * 2;    // 1.9 MB
  const size_t w1pp  = (size_t)256 * 8192 * 2;        // 4 MB per predicate

  unsigned short* featbf = (unsigned short*)ws;
  unsigned short* w2t    = (unsigned short*)(ws + featB);
  unsigned short* w1t    = (unsigned short*)(ws + featB + w2B);

  size_t base = featB + w2B;
  size_t rem = (ws_size > base) ? (ws_size - base) : 0;
  int CH = (int)(rem / w1pp);
  if (CH > 29) CH = 29;
  if (CH < 1) CH = 1;

  k_cvt_feat<<<2048, 256, 0, stream>>>(features, featbf);
  k_cvt_w2<<<29, 256, 0, stream>>>(W2, w2t);

  for (int p0 = 0; p0 < 29; p0 += CH) {
    int c = (29 - p0) < CH ? (29 - p0) : CH;
    k_cvt_w1<<<dim3(32, 4, c), 256, 0, stream>>>(W1, w1t, p0);
    k_gemm1<<<dim3(16, c), 512, 0, stream>>>(featbf, w1t, b1, w2t, b2, W3, b3, out, p0);
  }
}